// Round 1
// baseline (381.483 us; speedup 1.0000x reference)
//
#include <hip/hip_runtime.h>
#include <math.h>

#define NN 100000      // nodes
#define NE 1600000     // edges
#define C  32          // channels
#define CAP 48         // per-node bucket capacity (Poisson(16) tail @48 ~1e-11)

#define WQ_SCALE 32767.0f
#define INV_WQ   (1.0f/32767.0f)

typedef __attribute__((ext_vector_type(8))) short short8;   // 8 bf16 (4 VGPRs)
typedef __attribute__((ext_vector_type(4))) float floatx4;  // MFMA acc

// round-to-nearest-even bf16 bits (low 16)
__device__ __forceinline__ unsigned rn_bf16(float f) {
    unsigned b = __float_as_uint(f);
    return (b + 0x7fffu + ((b >> 16) & 1u)) >> 16;
}

__device__ __forceinline__ float sigm(float a) { return 1.f / (1.f + expf(-a)); }

// bucket entry: src (17b) << 15 | wq (15b)
__device__ __forceinline__ unsigned enc_edge(int s, float w) {
    int wq = (int)(w * WQ_SCALE + 0.5f);
    wq = wq > 32767 ? 32767 : wq;
    return ((unsigned)s << 15) | (unsigned)wq;
}

// pack hi/lo 16-bit halves of 8 uints into a bf16x8 fragment
__device__ __forceinline__ short8 pack_hi8(uint4 a, uint4 b) {
    short8 v;
    v[0] = (short)(a.x >> 16); v[1] = (short)(a.y >> 16);
    v[2] = (short)(a.z >> 16); v[3] = (short)(a.w >> 16);
    v[4] = (short)(b.x >> 16); v[5] = (short)(b.y >> 16);
    v[6] = (short)(b.z >> 16); v[7] = (short)(b.w >> 16);
    return v;
}
__device__ __forceinline__ short8 pack_lo8(uint4 a, uint4 b) {
    short8 v;
    v[0] = (short)(a.x & 0xffffu); v[1] = (short)(a.y & 0xffffu);
    v[2] = (short)(a.z & 0xffffu); v[3] = (short)(a.w & 0xffffu);
    v[4] = (short)(b.x & 0xffffu); v[5] = (short)(b.y & 0xffffu);
    v[6] = (short)(b.z & 0xffffu); v[7] = (short)(b.w & 0xffffu);
    return v;
}

// ---------------------------------------------------------------------------
// Direct edge scatter (replaces bin_pass + bin_build).
// Per edge: deg[src] += w (float atomic); pos = atomicAdd(cursor[dst]);
// buckets[dst*CAP+pos] = enc(src,w). A node's ~16 entries share 1-2 L2 lines,
// so the 4B scattered stores coalesce in L2 (~10 MB dirty write-back total).
// 4 edges/thread with int4/float4 edge loads; grid 1563 blocks (~6/CU).
// ---------------------------------------------------------------------------
__global__ __launch_bounds__(256) void edge_scatter(const int* __restrict__ ei,
                                                    const float* __restrict__ w,
                                                    float* __restrict__ deg,
                                                    int* __restrict__ cursor,
                                                    unsigned* __restrict__ buckets) {
    int e0 = (blockIdx.x * 256 + threadIdx.x) * 4;
    if (e0 >= NE) return;                       // NE % 4 == 0: full int4 safe
    int4   s4 = *(const int4*)(ei + e0);
    int4   d4 = *(const int4*)(ei + NE + e0);
    float4 w4 = *(const float4*)(w + e0);
    int   ss[4] = {s4.x, s4.y, s4.z, s4.w};
    int   dd[4] = {d4.x, d4.y, d4.z, d4.w};
    float ww[4] = {w4.x, w4.y, w4.z, w4.w};
#pragma unroll
    for (int i = 0; i < 4; ++i) {
        atomicAdd(&deg[ss[i]], ww[i]);
        int pos = atomicAdd(&cursor[dd[i]], 1);
        if (pos < CAP)
            buckets[(size_t)dd[i] * CAP + pos] = enc_edge(ss[i], ww[i]);
    }
}

// ---------------------------------------------------------------------------
// dis = deg>0 ? rsqrt(deg) : 0 (computed here, redundantly per channel);
// xh2[t]   = pack( bf16(dis*x) | bf16(dis*h) )   (prescaled, for gathers)
// xraw2[t] = pack( bf16(x)     | bf16(h)     )   (raw, for the MFMA gate)
// ---------------------------------------------------------------------------
__global__ __launch_bounds__(256) void build_xh(const float* __restrict__ x,
                                                const float* __restrict__ h,
                                                const float* __restrict__ deg,
                                                float* __restrict__ dis,
                                                unsigned* __restrict__ xh2,
                                                unsigned* __restrict__ xraw2) {
    int t = blockIdx.x * 256 + threadIdx.x;
    if (t >= NN * C) return;
    float dg = deg[t >> 5];
    float d = dg > 0.f ? rsqrtf(dg) : 0.f;
    if ((t & 31) == 0) dis[t >> 5] = d;
    float xv = x[t], hv = h[t];
    xh2[t]   = (rn_bf16(xv * d) << 16) | rn_bf16(hv * d);
    xraw2[t] = (rn_bf16(xv) << 16) | rn_bf16(hv);
}

// ---------------------------------------------------------------------------
// agg2[n][j] = pack( bf16(-dis_n * sum w*(dis_s*x_s)) | bf16(same for h) )
// ---------------------------------------------------------------------------
__global__ __launch_bounds__(256) void agg_xh(const unsigned* __restrict__ buckets,
                                              const int* __restrict__ cursor,
                                              const float* __restrict__ dis,
                                              const unsigned* __restrict__ xh2,
                                              unsigned* __restrict__ agg2) {
    int tid = threadIdx.x;
    int nl = tid >> 5, j = tid & 31;
    int n = blockIdx.x * 8 + nl;
    if (n >= NN) return;
    int cnt = min(cursor[n], CAP);
    float ax0 = 0.f, ax1 = 0.f, ax2 = 0.f, ax3 = 0.f;
    float ah0 = 0.f, ah1 = 0.f, ah2 = 0.f, ah3 = 0.f;
    for (int base = 0; base < cnt; base += 32) {
        int idx = base + j;
        int sv = 0; float cv = 0.f;
        if (idx < cnt) {
            unsigned u = buckets[(size_t)n * CAP + idx];
            sv = (int)(u >> 15);
            cv = (float)(u & 32767u) * INV_WQ;
        }
        int mm = min(32, cnt - base);
        int i2 = 0;
        for (; i2 + 4 <= mm; i2 += 4) {
            int s0 = __shfl(sv, i2 + 0, 32); float c0 = __shfl(cv, i2 + 0, 32);
            int s1 = __shfl(sv, i2 + 1, 32); float c1 = __shfl(cv, i2 + 1, 32);
            int s2 = __shfl(sv, i2 + 2, 32); float c2 = __shfl(cv, i2 + 2, 32);
            int s3 = __shfl(sv, i2 + 3, 32); float c3 = __shfl(cv, i2 + 3, 32);
            unsigned u0 = xh2[(size_t)s0 * C + j];
            unsigned u1 = xh2[(size_t)s1 * C + j];
            unsigned u2 = xh2[(size_t)s2 * C + j];
            unsigned u3 = xh2[(size_t)s3 * C + j];
            ax0 = fmaf(c0, __uint_as_float(u0 & 0xffff0000u), ax0);
            ah0 = fmaf(c0, __uint_as_float(u0 << 16), ah0);
            ax1 = fmaf(c1, __uint_as_float(u1 & 0xffff0000u), ax1);
            ah1 = fmaf(c1, __uint_as_float(u1 << 16), ah1);
            ax2 = fmaf(c2, __uint_as_float(u2 & 0xffff0000u), ax2);
            ah2 = fmaf(c2, __uint_as_float(u2 << 16), ah2);
            ax3 = fmaf(c3, __uint_as_float(u3 & 0xffff0000u), ax3);
            ah3 = fmaf(c3, __uint_as_float(u3 << 16), ah3);
        }
        for (; i2 < mm; ++i2) {
            int s = __shfl(sv, i2, 32); float cf = __shfl(cv, i2, 32);
            unsigned u = xh2[(size_t)s * C + j];
            ax0 = fmaf(cf, __uint_as_float(u & 0xffff0000u), ax0);
            ah0 = fmaf(cf, __uint_as_float(u << 16), ah0);
        }
    }
    float disn = -dis[n];
    float ax = disn * ((ax0 + ax1) + (ax2 + ax3));
    float ah = disn * ((ah0 + ah1) + (ah2 + ah3));
    agg2[(size_t)n * C + j] = (rn_bf16(ax) << 16) | rn_bf16(ah);
}

// ---------------------------------------------------------------------------
// MFMA gate: [N x 128] (x|ax|h|ah bf16) @ [128 x 96] (Wz|Wr|Wp bf16).
// Wave = 16-node tile; 6 col-tiles (z0,z1,r0,r1,p0,p1); p skips h/ah chunks.
// 20 B-frags pre-swizzled in LDS. Outputs: hrz2 = bf16(h*r)|bf16(z),
// hr16 = bf16(dis*h*r), pout fp32.
// ---------------------------------------------------------------------------
__global__ __launch_bounds__(256) void gate_mfma(const unsigned* __restrict__ xraw2,
                                                 const unsigned* __restrict__ agg2,
                                                 const float* __restrict__ dis,
                                                 const float* __restrict__ Wx,
                                                 const float* __restrict__ Wh,
                                                 const float* __restrict__ bx,
                                                 const float* __restrict__ bh,
                                                 unsigned* __restrict__ hrz2,
                                                 unsigned short* __restrict__ hr16,
                                                 float* __restrict__ pout) {
    __shared__ __align__(16) unsigned short Bl[20][64][8];   // 20 KB
    int tid = threadIdx.x;
    // stage B fragments: frag layout [lane][8 bf16] = B[k=quad*8+i][col=lane&15]
    for (int i = tid; i < 20 * 64; i += 256) {
        int f = i >> 6, l = i & 63;
        int t, c;
        if (f < 16) { t = f >> 2; c = f & 3; }
        else        { t = 4 + ((f - 16) >> 1); c = (f - 16) & 1; }
        int g = t >> 1;
        int j = ((t & 1) << 4) + (l & 15);
        int kb = (l >> 4) << 3;
        const float* srcp = (c < 2 ? Wx : Wh) + g * 2048 + (c & 1) * 1024 + j;
        unsigned pk[4];
#pragma unroll
        for (int q = 0; q < 4; ++q) {
            unsigned lo = rn_bf16(srcp[(kb + 2 * q) * 32]);
            unsigned hi = rn_bf16(srcp[(kb + 2 * q + 1) * 32]);
            pk[q] = (hi << 16) | lo;
        }
        *(uint4*)(&Bl[f][l][0]) = make_uint4(pk[0], pk[1], pk[2], pk[3]);
    }

    int lane = tid & 63, wave = tid >> 6;
    int j0 = lane & 15, quad = lane >> 4;
    int tbase = blockIdx.x * 64 + wave * 16;
    int na = tbase + j0;                 // A-row m = lane&15
    short8 A0 = {0,0,0,0,0,0,0,0}, A1 = A0, A2 = A0, A3 = A0;
    if (na < NN) {
        const uint4* px = (const uint4*)(xraw2 + (size_t)na * C + quad * 8);
        uint4 xa = px[0], xb = px[1];
        A0 = pack_hi8(xa, xb);           // x
        A2 = pack_lo8(xa, xb);           // h
        const uint4* pg = (const uint4*)(agg2 + (size_t)na * C + quad * 8);
        uint4 ga = pg[0], gb = pg[1];
        A1 = pack_hi8(ga, gb);           // agg_x
        A3 = pack_lo8(ga, gb);           // agg_h
    }
    __syncthreads();

#define B8(f) (*(const short8*)(&Bl[f][lane][0]))
    floatx4 az0 = {0.f,0.f,0.f,0.f}, az1 = az0, ar0 = az0, ar1 = az0, ap0 = az0, ap1 = az0;
    az0 = __builtin_amdgcn_mfma_f32_16x16x32_bf16(A0, B8(0),  az0, 0, 0, 0);
    az0 = __builtin_amdgcn_mfma_f32_16x16x32_bf16(A1, B8(1),  az0, 0, 0, 0);
    az0 = __builtin_amdgcn_mfma_f32_16x16x32_bf16(A2, B8(2),  az0, 0, 0, 0);
    az0 = __builtin_amdgcn_mfma_f32_16x16x32_bf16(A3, B8(3),  az0, 0, 0, 0);
    az1 = __builtin_amdgcn_mfma_f32_16x16x32_bf16(A0, B8(4),  az1, 0, 0, 0);
    az1 = __builtin_amdgcn_mfma_f32_16x16x32_bf16(A1, B8(5),  az1, 0, 0, 0);
    az1 = __builtin_amdgcn_mfma_f32_16x16x32_bf16(A2, B8(6),  az1, 0, 0, 0);
    az1 = __builtin_amdgcn_mfma_f32_16x16x32_bf16(A3, B8(7),  az1, 0, 0, 0);
    ar0 = __builtin_amdgcn_mfma_f32_16x16x32_bf16(A0, B8(8),  ar0, 0, 0, 0);
    ar0 = __builtin_amdgcn_mfma_f32_16x16x32_bf16(A1, B8(9),  ar0, 0, 0, 0);
    ar0 = __builtin_amdgcn_mfma_f32_16x16x32_bf16(A2, B8(10), ar0, 0, 0, 0);
    ar0 = __builtin_amdgcn_mfma_f32_16x16x32_bf16(A3, B8(11), ar0, 0, 0, 0);
    ar1 = __builtin_amdgcn_mfma_f32_16x16x32_bf16(A0, B8(12), ar1, 0, 0, 0);
    ar1 = __builtin_amdgcn_mfma_f32_16x16x32_bf16(A1, B8(13), ar1, 0, 0, 0);
    ar1 = __builtin_amdgcn_mfma_f32_16x16x32_bf16(A2, B8(14), ar1, 0, 0, 0);
    ar1 = __builtin_amdgcn_mfma_f32_16x16x32_bf16(A3, B8(15), ar1, 0, 0, 0);
    ap0 = __builtin_amdgcn_mfma_f32_16x16x32_bf16(A0, B8(16), ap0, 0, 0, 0);
    ap0 = __builtin_amdgcn_mfma_f32_16x16x32_bf16(A1, B8(17), ap0, 0, 0, 0);
    ap1 = __builtin_amdgcn_mfma_f32_16x16x32_bf16(A0, B8(18), ap1, 0, 0, 0);
    ap1 = __builtin_amdgcn_mfma_f32_16x16x32_bf16(A1, B8(19), ap1, 0, 0, 0);
#undef B8

    // epilogue: C/D layout col=lane&15, row=quad*4+reg
    float bza = bx[j0]      + bh[j0];
    float bzb = bx[j0 + 16] + bh[j0 + 16];
    float bra = bx[32 + j0] + bh[32 + j0];
    float brb = bx[48 + j0] + bh[48 + j0];
    float bpa = bx[64 + j0] + bh[64 + j0];
    float bpb = bx[80 + j0] + bh[80 + j0];
#pragma unroll
    for (int p = 0; p < 4; ++p) {
        int nr = tbase + quad * 4 + p;
        if (nr >= NN) continue;
        float dn = dis[nr];
        size_t ra = (size_t)nr * C + j0;
        size_t rb = ra + 16;
        float ha = __uint_as_float(xraw2[ra] << 16);
        float hb = __uint_as_float(xraw2[rb] << 16);
        float za  = sigm(az0[p] + bza);
        float zb  = sigm(az1[p] + bzb);
        float rav = sigm(ar0[p] + bra);
        float rbv = sigm(ar1[p] + brb);
        float hra = ha * rav, hrb = hb * rbv;
        hrz2[ra] = (rn_bf16(hra) << 16) | rn_bf16(za);
        hrz2[rb] = (rn_bf16(hrb) << 16) | rn_bf16(zb);
        hr16[ra] = (unsigned short)rn_bf16(dn * hra);
        hr16[rb] = (unsigned short)rn_bf16(dn * hrb);
        pout[ra] = ap0[p] + bpa;
        pout[rb] = ap1[p] + bpb;
    }
}

// ---------------------------------------------------------------------------
// Fused: gather agg_hr from hr16; h~ = tanh(ph + (h*r)@Wh20 + agg_hr@Wh21);
// h_new = z*h + (1-z)*h~; out = softplus(relu(h_new)@Wl + bl).
// hr (bf16) and z (bf16) unpacked from hrz2.
// ---------------------------------------------------------------------------
__global__ __launch_bounds__(256) void final_kernel(const float* __restrict__ h,
                                                    const unsigned* __restrict__ hrz2,
                                                    const float* __restrict__ ph,
                                                    const unsigned* __restrict__ buckets,
                                                    const int* __restrict__ cursor,
                                                    const float* __restrict__ dis,
                                                    const unsigned short* __restrict__ hr16,
                                                    const float* __restrict__ Wh,
                                                    const float* __restrict__ Wl,
                                                    const float* __restrict__ bl,
                                                    float* __restrict__ out,
                                                    float* __restrict__ hnew) {
    __shared__ float sW[2 * 1024];
    __shared__ float sIn[2][8][C];
    int tid = threadIdx.x;
    for (int i = tid; i < 2 * 1024; i += 256) sW[i] = Wh[4096 + i]; // Wh20, Wh21
    int nl = tid >> 5, j = tid & 31;
    int n = blockIdx.x * 8 + nl;
    if (n >= NN) return;

    int cnt = min(cursor[n], CAP);
    float a0 = 0.f, a1 = 0.f, a2 = 0.f, a3 = 0.f;
    for (int base = 0; base < cnt; base += 32) {
        int idx = base + j;
        int sv = 0; float cv = 0.f;
        if (idx < cnt) {
            unsigned u = buckets[(size_t)n * CAP + idx];
            sv = (int)(u >> 15);
            cv = (float)(u & 32767u) * INV_WQ;
        }
        int mm = min(32, cnt - base);
        int i2 = 0;
        for (; i2 + 4 <= mm; i2 += 4) {
            int s0 = __shfl(sv, i2 + 0, 32); float c0 = __shfl(cv, i2 + 0, 32);
            int s1 = __shfl(sv, i2 + 1, 32); float c1 = __shfl(cv, i2 + 1, 32);
            int s2 = __shfl(sv, i2 + 2, 32); float c2 = __shfl(cv, i2 + 2, 32);
            int s3 = __shfl(sv, i2 + 3, 32); float c3 = __shfl(cv, i2 + 3, 32);
            float v0 = __uint_as_float(((unsigned)hr16[(size_t)s0 * C + j]) << 16);
            float v1 = __uint_as_float(((unsigned)hr16[(size_t)s1 * C + j]) << 16);
            float v2 = __uint_as_float(((unsigned)hr16[(size_t)s2 * C + j]) << 16);
            float v3 = __uint_as_float(((unsigned)hr16[(size_t)s3 * C + j]) << 16);
            a0 = fmaf(c0, v0, a0);
            a1 = fmaf(c1, v1, a1);
            a2 = fmaf(c2, v2, a2);
            a3 = fmaf(c3, v3, a3);
        }
        for (; i2 < mm; ++i2) {
            int s = __shfl(sv, i2, 32); float cf = __shfl(cv, i2, 32);
            a0 = fmaf(cf, __uint_as_float(((unsigned)hr16[(size_t)s * C + j]) << 16), a0);
        }
    }
    float ag = -dis[n] * ((a0 + a1) + (a2 + a3));
    unsigned uz = hrz2[(size_t)n * C + j];
    float hrv = __uint_as_float(uz & 0xffff0000u);
    float zv  = __uint_as_float(uz << 16);
    sIn[0][nl][j] = hrv;
    sIn[1][nl][j] = ag;
    __syncthreads();

    float acc = ph[(size_t)n * C + j];
#pragma unroll
    for (int k = 0; k < C; ++k) {
        int o = k * 32 + j;
        acc = fmaf(sIn[0][nl][k], sW[o], acc);
        acc = fmaf(sIn[1][nl][k], sW[1024 + o], acc);
    }
    float ht = tanhf(acc);
    float hv = h[(size_t)n * C + j];
    float hn = fmaf(zv, hv - ht, ht);
    hnew[(size_t)n * C + j] = hn;
    float p = fmaxf(hn, 0.f) * Wl[j];
#pragma unroll
    for (int off = 16; off; off >>= 1) p += __shfl_down(p, off, 32);
    if (j == 0) {
        float v = p + bl[0];
        out[n] = fmaxf(v, 0.f) + log1pf(expf(-fabsf(v)));
    }
}

// ---------------------------------------------------------------------------
extern "C" void kernel_launch(void* const* d_in, const int* in_sizes, int n_in,
                              void* d_out, int out_size, void* d_ws, size_t ws_size,
                              hipStream_t stream) {
    const float* x  = (const float*)d_in[0];
    const int*   ei = (const int*)d_in[1];
    const float* ew = (const float*)d_in[2];
    const float* h  = (const float*)d_in[3];
    const float* Wx = (const float*)d_in[4];
    const float* bx = (const float*)d_in[5];
    const float* Wh = (const float*)d_in[6];
    const float* bh = (const float*)d_in[7];
    const float* Wl = (const float*)d_in[8];
    const float* bl = (const float*)d_in[9];

    float* out  = (float*)d_out;        // [N,1]
    float* hnew = out + NN;             // [N,32]

    char* ws = (char*)d_ws;
    float*          deg    = (float*)ws;                            // NN
    int*            cursor = (int*)(deg + NN);                      // NN
    float*          dis    = (float*)(cursor + NN);                 // NN
    unsigned*       buckets= (unsigned*)(dis + NN);                 // NN*CAP
    unsigned*       xh2    = buckets + (size_t)NN * CAP;            // NN*C
    unsigned*       xraw2  = xh2 + (size_t)NN * C;                  // NN*C
    unsigned*       agg2   = xraw2 + (size_t)NN * C;                // NN*C
    float*          pbuf   = (float*)(agg2 + (size_t)NN * C);       // NN*C
    unsigned short* hr16   = (unsigned short*)(pbuf + (size_t)NN * C); // NN*C (2B)
    // alias (kernel-boundary safe): xh2 dead after agg_xh
    unsigned*       hrz2   = xh2;

    hipMemsetAsync(d_ws, 0, (size_t)NN * 8, stream);   // deg + cursor

    edge_scatter<<<(NE / 4 + 255) / 256, 256, 0, stream>>>(ei, ew, deg, cursor,
                                                           buckets);
    build_xh    <<<(NN * C + 255) / 256, 256, 0, stream>>>(x, h, deg, dis,
                                                           xh2, xraw2);
    agg_xh      <<<(NN + 7) / 8, 256, 0, stream>>>(buckets, cursor, dis, xh2, agg2);
    gate_mfma   <<<(NN + 63) / 64, 256, 0, stream>>>(xraw2, agg2, dis, Wx, Wh,
                                                     bx, bh, hrz2, hr16, pbuf);
    final_kernel<<<(NN + 7) / 8, 256, 0, stream>>>(h, hrz2, pbuf,
                                                   buckets, cursor, dis, hr16,
                                                   Wh, Wl, bl, out, hnew);
}

// Round 2
// 328.840 us; speedup vs baseline: 1.1601x; 1.1601x over previous
//
#include <hip/hip_runtime.h>
#include <math.h>

#define NN 100000      // nodes
#define NE 1600000     // edges
#define C  32          // channels
#define CAP 48         // per-node bucket capacity (Poisson(16) tail @48 ~1e-11)

#define BSH    8       // 256 nodes per bin
#define BNODES 256
#define NB     392     // ceil(100352/256)
#define NSUB   8       // XCD-congruence sub-regions per bin (sub = blockIdx.x & 7)
#define SUBCAP 768     // edges per (bin,sub) region (mean 510, +11 sigma)
#define EPB    2048    // edges per bin_pass block (= 256 threads * 8)

#define WQ_SCALE 32767.0f
#define INV_WQ   (1.0f/32767.0f)

typedef __attribute__((ext_vector_type(8))) short short8;   // 8 bf16 (4 VGPRs)
typedef __attribute__((ext_vector_type(4))) float floatx4;  // MFMA acc

// round-to-nearest-even bf16 bits (low 16)
__device__ __forceinline__ unsigned rn_bf16(float f) {
    unsigned b = __float_as_uint(f);
    return (b + 0x7fffu + ((b >> 16) & 1u)) >> 16;
}

__device__ __forceinline__ float sigm(float a) { return 1.f / (1.f + expf(-a)); }

// bucket entry: src (17b) << 15 | wq (15b)
__device__ __forceinline__ unsigned enc_edge(int s, float w) {
    int wq = (int)(w * WQ_SCALE + 0.5f);
    wq = wq > 32767 ? 32767 : wq;
    return ((unsigned)s << 15) | (unsigned)wq;
}

// pack hi/lo 16-bit halves of 8 uints into a bf16x8 fragment
__device__ __forceinline__ short8 pack_hi8(uint4 a, uint4 b) {
    short8 v;
    v[0] = (short)(a.x >> 16); v[1] = (short)(a.y >> 16);
    v[2] = (short)(a.z >> 16); v[3] = (short)(a.w >> 16);
    v[4] = (short)(b.x >> 16); v[5] = (short)(b.y >> 16);
    v[6] = (short)(b.z >> 16); v[7] = (short)(b.w >> 16);
    return v;
}
__device__ __forceinline__ short8 pack_lo8(uint4 a, uint4 b) {
    short8 v;
    v[0] = (short)(a.x & 0xffffu); v[1] = (short)(a.y & 0xffffu);
    v[2] = (short)(a.z & 0xffffu); v[3] = (short)(a.w & 0xffffu);
    v[4] = (short)(b.x & 0xffffu); v[5] = (short)(b.y & 0xffffu);
    v[6] = (short)(b.z & 0xffffu); v[7] = (short)(b.w & 0xffffu);
    return v;
}

// ---------------------------------------------------------------------------
// Pass 1: bin edges by dst>>8 into per-(bin, blockIdx&7) sub-regions so that
// blocks sharing a region share an XCD (default round-robin bid->XCD map) ->
// full-line write-back instead of cross-XCD partial lines.
// Record: enc4 (src<<15|wq, 4B) + d8 (dst&255, 1B). deg[src] via direct
// float atomics (fire-and-forget, replaces the whole srec path).
// ---------------------------------------------------------------------------
__global__ __launch_bounds__(256) void bin_pass(const int* __restrict__ ei,
                                                const float* __restrict__ w,
                                                int* __restrict__ gbin,
                                                unsigned* __restrict__ enc4,
                                                unsigned char* __restrict__ d8a,
                                                float* __restrict__ deg) {
    __shared__ int hd[NB], bd[NB];
    int tid = threadIdx.x;
    int sub = blockIdx.x & (NSUB - 1);
    for (int i = tid; i < NB; i += 256) hd[i] = 0;
    __syncthreads();
    int e0 = blockIdx.x * EPB;
    int dloc[8];
#pragma unroll
    for (int k = 0; k < 8; ++k) {
        int e = e0 + tid + k * 256;
        int d = (e < NE) ? ei[NE + e] : -1;
        dloc[k] = d;
        if (d >= 0) atomicAdd(&hd[d >> BSH], 1);
    }
    __syncthreads();
    for (int i = tid; i < NB; i += 256)
        bd[i] = hd[i] ? atomicAdd(&gbin[sub * NB + i], hd[i]) : 0;
    __syncthreads();
    for (int i = tid; i < NB; i += 256) hd[i] = 0;   // cursors
    __syncthreads();
#pragma unroll
    for (int k = 0; k < 8; ++k) {
        int d = dloc[k];
        if (d < 0) continue;
        int e = e0 + tid + k * 256;
        int s = ei[e];
        float we = w[e];
        atomicAdd(&deg[s], we);
        int bin = d >> BSH;
        int off = bd[bin] + atomicAdd(&hd[bin], 1);
        if (off < SUBCAP) {
            size_t base = ((size_t)bin * NSUB + sub) * SUBCAP + off;
            enc4[base] = enc_edge(s, we);
            d8a[base]  = (unsigned char)(d & (BNODES - 1));
        }
    }
}

// ---------------------------------------------------------------------------
// Pass 2: one block per bin (512 threads). LDS bucket scatter -> coalesced
// write; dis = rsqrt(deg).
// ---------------------------------------------------------------------------
__global__ __launch_bounds__(512) void bin_build(const unsigned* __restrict__ enc4,
                                                 const unsigned char* __restrict__ d8a,
                                                 const int* __restrict__ gbin,
                                                 const float* __restrict__ deg,
                                                 unsigned* __restrict__ buckets,
                                                 int* __restrict__ cursor,
                                                 float* __restrict__ dis) {
    __shared__ __align__(16) unsigned lbuck[BNODES * CAP];   // 48 KB
    __shared__ int lcur[BNODES];
    int b = blockIdx.x, tid = threadIdx.x;
    if (tid < BNODES) lcur[tid] = 0;
    __syncthreads();
#pragma unroll
    for (int sub = 0; sub < NSUB; ++sub) {
        int cnt = min(gbin[sub * NB + b], SUBCAP);
        size_t base = ((size_t)b * NSUB + sub) * SUBCAP;
        for (int i = tid; i < cnt; i += 512) {
            unsigned enc = enc4[base + i];
            int d8 = d8a[base + i];
            int pos = atomicAdd(&lcur[d8], 1);
            if (pos < CAP) lbuck[d8 * CAP + pos] = enc;
        }
    }
    __syncthreads();
    uint4* gb = (uint4*)(buckets + (size_t)b * BNODES * CAP);
    const uint4* lb = (const uint4*)lbuck;
    for (int i = tid; i < BNODES * CAP / 4; i += 512) gb[i] = lb[i];
    int n = b * BNODES + tid;
    if (tid < BNODES && n < NN) {
        cursor[n] = min(lcur[tid], CAP);
        float dg = deg[n];
        dis[n] = dg > 0.f ? rsqrtf(dg) : 0.f;
    }
}

// ---------------------------------------------------------------------------
// xh2[t]   = pack( bf16(dis*x) | bf16(dis*h) )   (prescaled, for gathers)
// xraw2[t] = pack( bf16(x)     | bf16(h)     )   (raw, for the MFMA gate)
// ---------------------------------------------------------------------------
__global__ __launch_bounds__(256) void build_xh(const float* __restrict__ x,
                                                const float* __restrict__ h,
                                                const float* __restrict__ dis,
                                                unsigned* __restrict__ xh2,
                                                unsigned* __restrict__ xraw2) {
    int t = blockIdx.x * 256 + threadIdx.x;
    if (t >= NN * C) return;
    float d = dis[t >> 5];
    float xv = x[t], hv = h[t];
    xh2[t]   = (rn_bf16(xv * d) << 16) | rn_bf16(hv * d);
    xraw2[t] = (rn_bf16(xv) << 16) | rn_bf16(hv);
}

// ---------------------------------------------------------------------------
// agg2[n][j] = pack( bf16(-dis_n * sum w*(dis_s*x_s)) | bf16(same for h) )
// ---------------------------------------------------------------------------
__global__ __launch_bounds__(256) void agg_xh(const unsigned* __restrict__ buckets,
                                              const int* __restrict__ cursor,
                                              const float* __restrict__ dis,
                                              const unsigned* __restrict__ xh2,
                                              unsigned* __restrict__ agg2) {
    int tid = threadIdx.x;
    int nl = tid >> 5, j = tid & 31;
    int n = blockIdx.x * 8 + nl;
    if (n >= NN) return;
    int cnt = min(cursor[n], CAP);
    float ax0 = 0.f, ax1 = 0.f, ax2 = 0.f, ax3 = 0.f;
    float ah0 = 0.f, ah1 = 0.f, ah2 = 0.f, ah3 = 0.f;
    for (int base = 0; base < cnt; base += 32) {
        int idx = base + j;
        int sv = 0; float cv = 0.f;
        if (idx < cnt) {
            unsigned u = buckets[(size_t)n * CAP + idx];
            sv = (int)(u >> 15);
            cv = (float)(u & 32767u) * INV_WQ;
        }
        int mm = min(32, cnt - base);
        int i2 = 0;
        for (; i2 + 4 <= mm; i2 += 4) {
            int s0 = __shfl(sv, i2 + 0, 32); float c0 = __shfl(cv, i2 + 0, 32);
            int s1 = __shfl(sv, i2 + 1, 32); float c1 = __shfl(cv, i2 + 1, 32);
            int s2 = __shfl(sv, i2 + 2, 32); float c2 = __shfl(cv, i2 + 2, 32);
            int s3 = __shfl(sv, i2 + 3, 32); float c3 = __shfl(cv, i2 + 3, 32);
            unsigned u0 = xh2[(size_t)s0 * C + j];
            unsigned u1 = xh2[(size_t)s1 * C + j];
            unsigned u2 = xh2[(size_t)s2 * C + j];
            unsigned u3 = xh2[(size_t)s3 * C + j];
            ax0 = fmaf(c0, __uint_as_float(u0 & 0xffff0000u), ax0);
            ah0 = fmaf(c0, __uint_as_float(u0 << 16), ah0);
            ax1 = fmaf(c1, __uint_as_float(u1 & 0xffff0000u), ax1);
            ah1 = fmaf(c1, __uint_as_float(u1 << 16), ah1);
            ax2 = fmaf(c2, __uint_as_float(u2 & 0xffff0000u), ax2);
            ah2 = fmaf(c2, __uint_as_float(u2 << 16), ah2);
            ax3 = fmaf(c3, __uint_as_float(u3 & 0xffff0000u), ax3);
            ah3 = fmaf(c3, __uint_as_float(u3 << 16), ah3);
        }
        for (; i2 < mm; ++i2) {
            int s = __shfl(sv, i2, 32); float cf = __shfl(cv, i2, 32);
            unsigned u = xh2[(size_t)s * C + j];
            ax0 = fmaf(cf, __uint_as_float(u & 0xffff0000u), ax0);
            ah0 = fmaf(cf, __uint_as_float(u << 16), ah0);
        }
    }
    float disn = -dis[n];
    float ax = disn * ((ax0 + ax1) + (ax2 + ax3));
    float ah = disn * ((ah0 + ah1) + (ah2 + ah3));
    agg2[(size_t)n * C + j] = (rn_bf16(ax) << 16) | rn_bf16(ah);
}

// ---------------------------------------------------------------------------
// MFMA gate: [N x 128] (x|ax|h|ah bf16) @ [128 x 96] (Wz|Wr|Wp bf16).
// Wave = 16-node tile; 6 col-tiles (z0,z1,r0,r1,p0,p1); p skips h/ah chunks.
// 20 B-frags pre-swizzled in LDS. Outputs: hrz2 = bf16(h*r)|bf16(z),
// hr16 = bf16(dis*h*r), pout fp32.
// ---------------------------------------------------------------------------
__global__ __launch_bounds__(256) void gate_mfma(const unsigned* __restrict__ xraw2,
                                                 const unsigned* __restrict__ agg2,
                                                 const float* __restrict__ dis,
                                                 const float* __restrict__ Wx,
                                                 const float* __restrict__ Wh,
                                                 const float* __restrict__ bx,
                                                 const float* __restrict__ bh,
                                                 unsigned* __restrict__ hrz2,
                                                 unsigned short* __restrict__ hr16,
                                                 float* __restrict__ pout) {
    __shared__ __align__(16) unsigned short Bl[20][64][8];   // 20 KB
    int tid = threadIdx.x;
    // stage B fragments: frag layout [lane][8 bf16] = B[k=quad*8+i][col=lane&15]
    for (int i = tid; i < 20 * 64; i += 256) {
        int f = i >> 6, l = i & 63;
        int t, c;
        if (f < 16) { t = f >> 2; c = f & 3; }
        else        { t = 4 + ((f - 16) >> 1); c = (f - 16) & 1; }
        int g = t >> 1;
        int j = ((t & 1) << 4) + (l & 15);
        int kb = (l >> 4) << 3;
        const float* srcp = (c < 2 ? Wx : Wh) + g * 2048 + (c & 1) * 1024 + j;
        unsigned pk[4];
#pragma unroll
        for (int q = 0; q < 4; ++q) {
            unsigned lo = rn_bf16(srcp[(kb + 2 * q) * 32]);
            unsigned hi = rn_bf16(srcp[(kb + 2 * q + 1) * 32]);
            pk[q] = (hi << 16) | lo;
        }
        *(uint4*)(&Bl[f][l][0]) = make_uint4(pk[0], pk[1], pk[2], pk[3]);
    }

    int lane = tid & 63, wave = tid >> 6;
    int j0 = lane & 15, quad = lane >> 4;
    int tbase = blockIdx.x * 64 + wave * 16;
    int na = tbase + j0;                 // A-row m = lane&15
    short8 A0 = {0,0,0,0,0,0,0,0}, A1 = A0, A2 = A0, A3 = A0;
    if (na < NN) {
        const uint4* px = (const uint4*)(xraw2 + (size_t)na * C + quad * 8);
        uint4 xa = px[0], xb = px[1];
        A0 = pack_hi8(xa, xb);           // x
        A2 = pack_lo8(xa, xb);           // h
        const uint4* pg = (const uint4*)(agg2 + (size_t)na * C + quad * 8);
        uint4 ga = pg[0], gb = pg[1];
        A1 = pack_hi8(ga, gb);           // agg_x
        A3 = pack_lo8(ga, gb);           // agg_h
    }
    __syncthreads();

#define B8(f) (*(const short8*)(&Bl[f][lane][0]))
    floatx4 az0 = {0.f,0.f,0.f,0.f}, az1 = az0, ar0 = az0, ar1 = az0, ap0 = az0, ap1 = az0;
    az0 = __builtin_amdgcn_mfma_f32_16x16x32_bf16(A0, B8(0),  az0, 0, 0, 0);
    az0 = __builtin_amdgcn_mfma_f32_16x16x32_bf16(A1, B8(1),  az0, 0, 0, 0);
    az0 = __builtin_amdgcn_mfma_f32_16x16x32_bf16(A2, B8(2),  az0, 0, 0, 0);
    az0 = __builtin_amdgcn_mfma_f32_16x16x32_bf16(A3, B8(3),  az0, 0, 0, 0);
    az1 = __builtin_amdgcn_mfma_f32_16x16x32_bf16(A0, B8(4),  az1, 0, 0, 0);
    az1 = __builtin_amdgcn_mfma_f32_16x16x32_bf16(A1, B8(5),  az1, 0, 0, 0);
    az1 = __builtin_amdgcn_mfma_f32_16x16x32_bf16(A2, B8(6),  az1, 0, 0, 0);
    az1 = __builtin_amdgcn_mfma_f32_16x16x32_bf16(A3, B8(7),  az1, 0, 0, 0);
    ar0 = __builtin_amdgcn_mfma_f32_16x16x32_bf16(A0, B8(8),  ar0, 0, 0, 0);
    ar0 = __builtin_amdgcn_mfma_f32_16x16x32_bf16(A1, B8(9),  ar0, 0, 0, 0);
    ar0 = __builtin_amdgcn_mfma_f32_16x16x32_bf16(A2, B8(10), ar0, 0, 0, 0);
    ar0 = __builtin_amdgcn_mfma_f32_16x16x32_bf16(A3, B8(11), ar0, 0, 0, 0);
    ar1 = __builtin_amdgcn_mfma_f32_16x16x32_bf16(A0, B8(12), ar1, 0, 0, 0);
    ar1 = __builtin_amdgcn_mfma_f32_16x16x32_bf16(A1, B8(13), ar1, 0, 0, 0);
    ar1 = __builtin_amdgcn_mfma_f32_16x16x32_bf16(A2, B8(14), ar1, 0, 0, 0);
    ar1 = __builtin_amdgcn_mfma_f32_16x16x32_bf16(A3, B8(15), ar1, 0, 0, 0);
    ap0 = __builtin_amdgcn_mfma_f32_16x16x32_bf16(A0, B8(16), ap0, 0, 0, 0);
    ap0 = __builtin_amdgcn_mfma_f32_16x16x32_bf16(A1, B8(17), ap0, 0, 0, 0);
    ap1 = __builtin_amdgcn_mfma_f32_16x16x32_bf16(A0, B8(18), ap1, 0, 0, 0);
    ap1 = __builtin_amdgcn_mfma_f32_16x16x32_bf16(A1, B8(19), ap1, 0, 0, 0);
#undef B8

    // epilogue: C/D layout col=lane&15, row=quad*4+reg
    float bza = bx[j0]      + bh[j0];
    float bzb = bx[j0 + 16] + bh[j0 + 16];
    float bra = bx[32 + j0] + bh[32 + j0];
    float brb = bx[48 + j0] + bh[48 + j0];
    float bpa = bx[64 + j0] + bh[64 + j0];
    float bpb = bx[80 + j0] + bh[80 + j0];
#pragma unroll
    for (int p = 0; p < 4; ++p) {
        int nr = tbase + quad * 4 + p;
        if (nr >= NN) continue;
        float dn = dis[nr];
        size_t ra = (size_t)nr * C + j0;
        size_t rb = ra + 16;
        float ha = __uint_as_float(xraw2[ra] << 16);
        float hb = __uint_as_float(xraw2[rb] << 16);
        float za  = sigm(az0[p] + bza);
        float zb  = sigm(az1[p] + bzb);
        float rav = sigm(ar0[p] + bra);
        float rbv = sigm(ar1[p] + brb);
        float hra = ha * rav, hrb = hb * rbv;
        hrz2[ra] = (rn_bf16(hra) << 16) | rn_bf16(za);
        hrz2[rb] = (rn_bf16(hrb) << 16) | rn_bf16(zb);
        hr16[ra] = (unsigned short)rn_bf16(dn * hra);
        hr16[rb] = (unsigned short)rn_bf16(dn * hrb);
        pout[ra] = ap0[p] + bpa;
        pout[rb] = ap1[p] + bpb;
    }
}

// ---------------------------------------------------------------------------
// Fused: gather agg_hr from hr16; h~ = tanh(ph + (h*r)@Wh20 + agg_hr@Wh21);
// h_new = z*h + (1-z)*h~; out = softplus(relu(h_new)@Wl + bl).
// hr (bf16) and z (bf16) unpacked from hrz2.
// ---------------------------------------------------------------------------
__global__ __launch_bounds__(256) void final_kernel(const float* __restrict__ h,
                                                    const unsigned* __restrict__ hrz2,
                                                    const float* __restrict__ ph,
                                                    const unsigned* __restrict__ buckets,
                                                    const int* __restrict__ cursor,
                                                    const float* __restrict__ dis,
                                                    const unsigned short* __restrict__ hr16,
                                                    const float* __restrict__ Wh,
                                                    const float* __restrict__ Wl,
                                                    const float* __restrict__ bl,
                                                    float* __restrict__ out,
                                                    float* __restrict__ hnew) {
    __shared__ float sW[2 * 1024];
    __shared__ float sIn[2][8][C];
    int tid = threadIdx.x;
    for (int i = tid; i < 2 * 1024; i += 256) sW[i] = Wh[4096 + i]; // Wh20, Wh21
    int nl = tid >> 5, j = tid & 31;
    int n = blockIdx.x * 8 + nl;
    if (n >= NN) return;

    int cnt = min(cursor[n], CAP);
    float a0 = 0.f, a1 = 0.f, a2 = 0.f, a3 = 0.f;
    for (int base = 0; base < cnt; base += 32) {
        int idx = base + j;
        int sv = 0; float cv = 0.f;
        if (idx < cnt) {
            unsigned u = buckets[(size_t)n * CAP + idx];
            sv = (int)(u >> 15);
            cv = (float)(u & 32767u) * INV_WQ;
        }
        int mm = min(32, cnt - base);
        int i2 = 0;
        for (; i2 + 4 <= mm; i2 += 4) {
            int s0 = __shfl(sv, i2 + 0, 32); float c0 = __shfl(cv, i2 + 0, 32);
            int s1 = __shfl(sv, i2 + 1, 32); float c1 = __shfl(cv, i2 + 1, 32);
            int s2 = __shfl(sv, i2 + 2, 32); float c2 = __shfl(cv, i2 + 2, 32);
            int s3 = __shfl(sv, i2 + 3, 32); float c3 = __shfl(cv, i2 + 3, 32);
            float v0 = __uint_as_float(((unsigned)hr16[(size_t)s0 * C + j]) << 16);
            float v1 = __uint_as_float(((unsigned)hr16[(size_t)s1 * C + j]) << 16);
            float v2 = __uint_as_float(((unsigned)hr16[(size_t)s2 * C + j]) << 16);
            float v3 = __uint_as_float(((unsigned)hr16[(size_t)s3 * C + j]) << 16);
            a0 = fmaf(c0, v0, a0);
            a1 = fmaf(c1, v1, a1);
            a2 = fmaf(c2, v2, a2);
            a3 = fmaf(c3, v3, a3);
        }
        for (; i2 < mm; ++i2) {
            int s = __shfl(sv, i2, 32); float cf = __shfl(cv, i2, 32);
            a0 = fmaf(cf, __uint_as_float(((unsigned)hr16[(size_t)s * C + j]) << 16), a0);
        }
    }
    float ag = -dis[n] * ((a0 + a1) + (a2 + a3));
    unsigned uz = hrz2[(size_t)n * C + j];
    float hrv = __uint_as_float(uz & 0xffff0000u);
    float zv  = __uint_as_float(uz << 16);
    sIn[0][nl][j] = hrv;
    sIn[1][nl][j] = ag;
    __syncthreads();

    float acc = ph[(size_t)n * C + j];
#pragma unroll
    for (int k = 0; k < C; ++k) {
        int o = k * 32 + j;
        acc = fmaf(sIn[0][nl][k], sW[o], acc);
        acc = fmaf(sIn[1][nl][k], sW[1024 + o], acc);
    }
    float ht = tanhf(acc);
    float hv = h[(size_t)n * C + j];
    float hn = fmaf(zv, hv - ht, ht);
    hnew[(size_t)n * C + j] = hn;
    float p = fmaxf(hn, 0.f) * Wl[j];
#pragma unroll
    for (int off = 16; off; off >>= 1) p += __shfl_down(p, off, 32);
    if (j == 0) {
        float v = p + bl[0];
        out[n] = fmaxf(v, 0.f) + log1pf(expf(-fabsf(v)));
    }
}

// ---------------------------------------------------------------------------
extern "C" void kernel_launch(void* const* d_in, const int* in_sizes, int n_in,
                              void* d_out, int out_size, void* d_ws, size_t ws_size,
                              hipStream_t stream) {
    const float* x  = (const float*)d_in[0];
    const int*   ei = (const int*)d_in[1];
    const float* ew = (const float*)d_in[2];
    const float* h  = (const float*)d_in[3];
    const float* Wx = (const float*)d_in[4];
    const float* bx = (const float*)d_in[5];
    const float* Wh = (const float*)d_in[6];
    const float* bh = (const float*)d_in[7];
    const float* Wl = (const float*)d_in[8];
    const float* bl = (const float*)d_in[9];

    float* out  = (float*)d_out;        // [N,1]
    float* hnew = out + NN;             // [N,32]

    // workspace layout (all offsets 16B-aligned):
    //   gbin   16384 B   (NSUB*NB ints = 12544 used)
    //   deg    400000 B
    //   cursor 400000 B
    //   dis    400000 B
    //   U      12800000 B  (enc4 9,633,792 + d8a 2,408,448; xraw2 aliases U)
    //   buckets 19267584 B (NB*256*CAP*4)
    //   xh2    12800000 B  (hrz2 alias)
    //   agg2   12800000 B
    //   pbuf   12800000 B
    //   hr16    6400000 B
    char* ws = (char*)d_ws;
    int*            gbin   = (int*)ws;
    float*          deg    = (float*)(ws + 16384);
    int*            cursor = (int*)(ws + 16384 + 400000);
    float*          dis    = (float*)(ws + 16384 + 800000);
    char*           U      = ws + 16384 + 1200000;
    unsigned*       enc4   = (unsigned*)U;
    unsigned char*  d8a    = (unsigned char*)(U + (size_t)NB * NSUB * SUBCAP * 4);
    unsigned*       buckets= (unsigned*)(U + 12800000);
    unsigned*       xh2    = (unsigned*)(U + 12800000 + 19267584);
    unsigned*       agg2   = xh2 + (size_t)NN * C;
    float*          pbuf   = (float*)(agg2 + (size_t)NN * C);
    unsigned short* hr16   = (unsigned short*)(pbuf + (size_t)NN * C);
    // aliases (kernel-boundary safe):
    unsigned*       xraw2  = (unsigned*)U;   // enc4/d8a dead after bin_build
    unsigned*       hrz2   = xh2;            // xh2 dead after agg_xh

    hipMemsetAsync(d_ws, 0, 16384 + 400000, stream);   // gbin + deg

    bin_pass    <<<(NE + EPB - 1) / EPB, 256, 0, stream>>>(ei, ew, gbin,
                                                           enc4, d8a, deg);
    bin_build   <<<NB, 512, 0, stream>>>(enc4, d8a, gbin, deg,
                                         buckets, cursor, dis);
    build_xh    <<<(NN * C + 255) / 256, 256, 0, stream>>>(x, h, dis, xh2, xraw2);
    agg_xh      <<<(NN + 7) / 8, 256, 0, stream>>>(buckets, cursor, dis, xh2, agg2);
    gate_mfma   <<<(NN + 63) / 64, 256, 0, stream>>>(xraw2, agg2, dis, Wx, Wh,
                                                     bx, bh, hrz2, hr16, pbuf);
    final_kernel<<<(NN + 7) / 8, 256, 0, stream>>>(h, hrz2, pbuf,
                                                   buckets, cursor, dis, hr16,
                                                   Wh, Wl, bl, out, hnew);
}